// Round 5
// baseline (1090.297 us; speedup 1.0000x reference)
//
#include <hip/hip_runtime.h>

// TimeEncoder: out[n, :] = concat(W0[T[n,0]], W1[T[n,1]], W2[T[n,2]], W3[T[n,3]])
// N = 2,000,000 rows; tables (366|24|7|60)x32 fp32 (~58 KB total, cache-resident);
// output [N, 128] fp32 = 1.024 GB streaming write. Write-BW-bound; floor ~168 us
// of pure kernel time @ 6.3 TB/s.
//
// R2 post-mortem: out_size is byte-like (1.024e9); sizing from it alone wrote
// 4.096 GB, smashing pristine input copies -> post-timing divergence. Extent is
// now derived from in_sizes[0] (T is [N,4] int32) and clamped by out_size/4.
// R4 post-mortem: dur_us (1082) ~= R2 (1089) despite 4x less kernel write volume,
// and rocprof shows our kernel < 646 us (absent from top-5, which is all 650-us
// 4GB poison fills) -> score has a big fixed harness component. This round
// isolates the R4 variables: drop nontemporal stores + dual-chain split, back to
// the plain-store single-chain loop (R2's structure, which moved 4.3 GB in ~1.1ms).

typedef float f32x4 __attribute__((ext_vector_type(4)));

__global__ __launch_bounds__(256) void time_encoder_kernel(
    const int* __restrict__ T,     // [N, 4] row-major int32
    const float* __restrict__ W0,  // [366, 32]
    const float* __restrict__ W1,  // [24, 32]
    const float* __restrict__ W2,  // [7, 32]
    const float* __restrict__ W3,  // [60, 32]
    f32x4* __restrict__ out,       // f32x4 view of [N, 128]
    int n_items)                   // number of float4 slots = N * 32
{
    const int stride = gridDim.x * blockDim.x;
    for (int gid = blockIdx.x * blockDim.x + threadIdx.x; gid < n_items; gid += stride) {
        const int row  = gid >> 5;   // 32 float4-slots per output row
        const int slot = gid & 31;
        const int part = slot >> 3;  // which table (8 float4s each)
        const int sub  = slot & 7;   // float4 index within the 32-float part

        const int t = T[(row << 2) + part];

        // Predicated pointer select (8 lanes per part within a wave; compiler
        // emits v_cndmask chains, no divergent branches).
        const float* W = (part == 0) ? W0 : (part == 1) ? W1 : (part == 2) ? W2 : W3;

        // Lanes 0-7 read the same table row, consecutive 16B chunks -> 128B
        // contiguous per 8-lane group; tables are L1/L2-resident.
        const f32x4 v = *reinterpret_cast<const f32x4*>(W + t * 32 + (sub << 2));
        out[gid] = v;  // consecutive lanes -> consecutive 16B -> coalesced 1KB/wave
    }
}

extern "C" void kernel_launch(void* const* d_in, const int* in_sizes, int n_in,
                              void* d_out, int out_size, void* d_ws, size_t ws_size,
                              hipStream_t stream) {
    const int*   T  = (const int*)d_in[0];
    const float* W0 = (const float*)d_in[1];
    const float* W1 = (const float*)d_in[2];
    const float* W2 = (const float*)d_in[3];
    const float* W3 = (const float*)d_in[4];
    f32x4* out = (f32x4*)d_out;

    // True output extent from the INPUT shape: T is [N,4] int32.
    const long long N = (long long)in_sizes[0] / 4;
    const long long n_true = N * 32;                  // float4 slots in [N,128]
    const long long n_out  = (long long)out_size / 4; // byte-or-element safe clamp
    const long long n_ll = n_true < n_out ? n_true : n_out;
    const int n_items = (int)n_ll;

    const int block = 256;
    const int grid = 8192;  // 2M threads, ~32 items each via grid-stride

    time_encoder_kernel<<<grid, block, 0, stream>>>(T, W0, W1, W2, W3, out, n_items);
}